// Round 4
// baseline (704.230 us; speedup 1.0000x reference)
//
#include <hip/hip_runtime.h>
#include <hip/hip_bf16.h>
#include <cstdint>

#define BATCH 1024
#define NPRE  8192
#define NPOST 8192

typedef _Float16 half8  __attribute__((ext_vector_type(8)));
typedef _Float16 half4_t __attribute__((ext_vector_type(4)));
typedef float    float4_t __attribute__((ext_vector_type(4)));

__device__ constexpr float ALPHA_SYN = 0.8187307530779818f; // exp(-0.001/0.005)
__device__ constexpr float DT_C = 0.001f;

// ---------------------------------------------------------------- prep
// A = spikes * U * x1 (f16, ws); x_new (f32, d_out 2nd half); out prefill I_syn*alpha
__global__ __launch_bounds__(256) void prep_kernel(
    const float* __restrict__ spikes, const float* __restrict__ x_std,
    const float* __restrict__ I_syn,
    const float* __restrict__ log_tau_rec, const float* __restrict__ logit_U,
    _Float16* __restrict__ Ah, float* __restrict__ out)
{
    const float tau_rec   = expf(log_tau_rec[0]);
    const float alpha_rec = expf(-DT_C / tau_rec);
    const float U         = 1.0f / (1.0f + expf(-logit_U[0]));

    const size_t i = ((size_t)blockIdx.x * 256 + threadIdx.x) * 4;
    float4_t sp = *(const float4_t*)(spikes + i);
    float4_t xs = *(const float4_t*)(x_std + i);
    float4_t is = *(const float4_t*)(I_syn + i);
    float4_t xn, ipre;
    half4_t  a;
#pragma unroll
    for (int j = 0; j < 4; ++j) {
        float x1  = 1.0f - (1.0f - xs[j]) * alpha_rec;
        float av  = sp[j] * U * x1;
        a[j]      = (_Float16)av;
        float spc = fminf(fmaxf(sp[j], 0.0f), 1.0f);
        xn[j]     = x1 * (1.0f - U * spc);
        ipre[j]   = is[j] * ALPHA_SYN;
    }
    *(half4_t*)(Ah + i)                           = a;
    *(float4_t*)(out + (size_t)BATCH * NPOST + i) = xn;
    *(float4_t*)(out + i)                         = ipre;
}

// ---------------------------------------------------------------- transpose
// W (f32, K x N, n contiguous) -> Wt (f16, N x K, k contiguous)
__global__ __launch_bounds__(256) void transpose_kernel(
    const float* __restrict__ W, _Float16* __restrict__ Wt)
{
    __shared__ float tile[64][65];
    const int n0 = blockIdx.x * 64;
    const int k0 = blockIdx.y * 64;
    const int t  = threadIdx.x;
    const int rr = t >> 4;
    const int cc = t & 15;
#pragma unroll
    for (int it = 0; it < 4; ++it) {
        const int r = it * 16 + rr;
        float4_t v = *(const float4_t*)(W + (size_t)(k0 + r) * NPOST + n0 + cc * 4);
        tile[r][cc * 4 + 0] = v[0];
        tile[r][cc * 4 + 1] = v[1];
        tile[r][cc * 4 + 2] = v[2];
        tile[r][cc * 4 + 3] = v[3];
    }
    __syncthreads();
    const int n  = t >> 2;
    const int kc = (t & 3) * 16;
    half8 h0, h1;
#pragma unroll
    for (int j = 0; j < 8; ++j) h0[j] = (_Float16)tile[kc + j][n];
#pragma unroll
    for (int j = 0; j < 8; ++j) h1[j] = (_Float16)tile[kc + 8 + j][n];
    _Float16* dst = Wt + (size_t)(n0 + n) * NPRE + k0 + kc;
    *(half8*)(dst)     = h0;
    *(half8*)(dst + 8) = h1;
}

// ---------------------------------------------------------------- GEMM
// 256x256 tile, BK=32, 8 waves (2Mx4N), 3-buffer LDS (96 KB), prefetch-2,
// counted vmcnt(4) (never 0 mid-loop), T2 slot-swizzle, T5 setprio, T1 XCD map.
#define BM 256
#define BN 256
#define BK 32
#define SPLITK 2
#define KSPAN (NPRE / SPLITK)   // 4096
#define NT (KSPAN / BK)         // 128 K-tiles per block

__device__ __forceinline__ void gload_lds16(const _Float16* g, _Float16* l) {
    __builtin_amdgcn_global_load_lds(
        (const __attribute__((address_space(1))) void*)g,
        (__attribute__((address_space(3))) void*)l, 16, 0, 0);
}

__global__ __launch_bounds__(512, 2) void gemm_kernel(
    const _Float16* __restrict__ Ah, const _Float16* __restrict__ Wt,
    const float* __restrict__ noise,
    const float* __restrict__ log_strength, float* __restrict__ out)
{
    // buffer = [256 rows][4 slots of 8 halfs]; slot s of row r holds k-piece s^((r>>1)&3)
    __shared__ _Float16 As[3][BM * BK];   // 16 KB each
    __shared__ _Float16 Bs[3][BN * BK];

    const int tid  = threadIdx.x;
    const int lane = tid & 63;
    const int wid  = tid >> 6;    // 0..7
    const int wr   = wid >> 2;    // 0..1  (M half: rows wr*128)
    const int wc   = wid & 3;     // 0..3  (N quarter: cols wc*64)

    // T1: XCD-grouped decode — 4 M-blocks x 2 splits of one n-panel share an XCD
    const int idx   = blockIdx.x;            // 0..255
    const int xcd   = idx & 7;
    const int rank  = idx >> 3;              // 0..31
    const int nblk  = xcd * 4 + (rank & 3);  // 0..31
    const int mblk  = (rank >> 2) & 3;       // 0..3
    const int split = rank >> 4;             // 0..1
    const int bm0   = mblk * BM;
    const int bn0   = nblk * BN;
    const int kbase = split * KSPAN;

    // ---- staging geometry (per wave: 4 gloads/stage = 2 A + 2 B)
    // lane -> row r0 = wid*16 + (lane>>2) (+ j*128), LDS slot sl = lane&3.
    // global piece p = sl ^ ((row>>1)&3); j*128 doesn't affect (row>>1)&3.
    const int r0   = wid * 16 + (lane >> 2);       // 0..127
    const int sl   = lane & 3;
    const int cswz = (r0 >> 1) & 3;
    const int pp   = sl ^ cswz;
    const _Float16* agbase = Ah + (size_t)(bm0 + r0) * NPRE + kbase + pp * 8;
    const _Float16* bgbase = Wt + (size_t)(bn0 + r0) * NPRE + kbase + pp * 8;
    const int ldsw = wid * 512;                    // wave-uniform LDS base (halfs)

#define STAGE_A(nb, t)                                                        \
    {                                                                         \
        gload_lds16(agbase + (size_t)(t) * BK, &As[nb][ldsw]);                \
        gload_lds16(agbase + (size_t)128 * NPRE + (size_t)(t) * BK,           \
                    &As[nb][4096 + ldsw]);                                    \
    }
#define STAGE_B(nb, t)                                                        \
    {                                                                         \
        gload_lds16(bgbase + (size_t)(t) * BK, &Bs[nb][ldsw]);                \
        gload_lds16(bgbase + (size_t)128 * NPRE + (size_t)(t) * BK,           \
                    &Bs[nb][4096 + ldsw]);                                    \
    }

    // ---- fragment read offsets (halfs). row*32 + swizzled-slot*8.
    // (row>>1)&3 == (l16>>1)&3 for all frag rows (other terms are mult of 4).
    const int l16 = lane & 15;
    const int lq  = lane >> 4;
    const int fsw = (lq ^ ((l16 >> 1) & 3)) * 8;
    int offA0[4], offA1[4], offB[4];
#pragma unroll
    for (int m = 0; m < 4; ++m) {
        offA0[m] = (wr * 128 + m * 16 + l16) * 32 + fsw;
        offA1[m] = (wr * 128 + (4 + m) * 16 + l16) * 32 + fsw;
    }
#pragma unroll
    for (int n = 0; n < 4; ++n)
        offB[n] = (wc * 64 + n * 16 + l16) * 32 + fsw;

    float4_t acc[8][4];
#pragma unroll
    for (int m = 0; m < 8; ++m)
#pragma unroll
        for (int n = 0; n < 4; ++n) acc[m][n] = {0.f, 0.f, 0.f, 0.f};

    // ---- prologue: tiles 0,1 staged into buffers 0,1
    STAGE_A(0, 0); STAGE_B(0, 0);
    STAGE_A(1, 1); STAGE_B(1, 1);

    for (int t = 0; t < NT; ++t) {
        const int cb = t % 3;
        const int pb = (t + 2) % 3;
        // stage(t) complete when only the newest 4 (stage t+1) remain in flight
        if (t < NT - 1) asm volatile("s_waitcnt vmcnt(4)" ::: "memory");
        else            asm volatile("s_waitcnt vmcnt(0)" ::: "memory");
        __builtin_amdgcn_s_barrier();
        const bool pf = (t + 2) < NT;

        // ---- phase A: stage A(t+2), read B frags + A frags (m half 0), 16 MFMA
        if (pf) STAGE_A(pb, t + 2);
        half8 bf[4], af[4];
#pragma unroll
        for (int n = 0; n < 4; ++n) bf[n] = *(const half8*)&Bs[cb][offB[n]];
#pragma unroll
        for (int m = 0; m < 4; ++m) af[m] = *(const half8*)&As[cb][offA0[m]];
        __builtin_amdgcn_s_setprio(1);
#pragma unroll
        for (int m = 0; m < 4; ++m)
#pragma unroll
            for (int n = 0; n < 4; ++n)
                acc[m][n] = __builtin_amdgcn_mfma_f32_16x16x32_f16(
                    af[m], bf[n], acc[m][n], 0, 0, 0);
        __builtin_amdgcn_s_setprio(0);
        __builtin_amdgcn_s_barrier();

        // ---- phase B: stage B(t+2), read A frags (m half 1), 16 MFMA
        if (pf) STAGE_B(pb, t + 2);
#pragma unroll
        for (int m = 0; m < 4; ++m) af[m] = *(const half8*)&As[cb][offA1[m]];
        __builtin_amdgcn_s_setprio(1);
#pragma unroll
        for (int m = 0; m < 4; ++m)
#pragma unroll
            for (int n = 0; n < 4; ++n)
                acc[4 + m][n] = __builtin_amdgcn_mfma_f32_16x16x32_f16(
                    af[m], bf[n], acc[4 + m][n], 0, 0, 0);
        __builtin_amdgcn_s_setprio(0);
        // next iteration's top barrier closes the tile
    }

    // ---- epilogue: out += s*acc*(1+0.15*noise) onto I_syn*alpha prefill
    const float s = expf(log_strength[0]);
    const int lq4 = lq * 4;
#pragma unroll
    for (int m = 0; m < 8; ++m) {
#pragma unroll
        for (int n = 0; n < 4; ++n) {
            const int col = bn0 + wc * 64 + n * 16 + l16;
#pragma unroll
            for (int r = 0; r < 4; ++r) {
                const int row = bm0 + wr * 128 + m * 16 + lq4 + r;
                const size_t o = (size_t)row * NPOST + col;
                const float v = acc[m][n][r] * s * (1.0f + noise[o] * 0.15f);
                unsafeAtomicAdd(&out[o], v);
            }
        }
    }
#undef STAGE_A
#undef STAGE_B
}

// ---------------------------------------------------------------- launch
extern "C" void kernel_launch(void* const* d_in, const int* in_sizes, int n_in,
                              void* d_out, int out_size, void* d_ws, size_t ws_size,
                              hipStream_t stream) {
    const float* spikes       = (const float*)d_in[0];
    const float* I_syn        = (const float*)d_in[1];
    const float* x_std        = (const float*)d_in[2];
    const float* noise        = (const float*)d_in[3];
    const float* Wnm          = (const float*)d_in[4];
    const float* log_strength = (const float*)d_in[5];
    const float* log_tau_rec  = (const float*)d_in[6];
    const float* logit_U      = (const float*)d_in[7];
    float* out = (float*)d_out;

    _Float16* Ah = (_Float16*)d_ws;                                     // 16 MB
    _Float16* Wt = (_Float16*)((char*)d_ws + (size_t)BATCH * NPRE * 2); // 128 MB

    prep_kernel<<<(BATCH * NPRE) / (256 * 4), 256, 0, stream>>>(
        spikes, x_std, I_syn, log_tau_rec, logit_U, Ah, out);
    transpose_kernel<<<dim3(NPOST / 64, NPRE / 64), 256, 0, stream>>>(Wnm, Wt);
    gemm_kernel<<<(NPOST / BN) * (BATCH / BM) * SPLITK, 512, 0, stream>>>(
        Ah, Wt, noise, log_strength, out);
}